// Round 11
// baseline (79.367 us; speedup 1.0000x reference)
//
#include <hip/hip_runtime.h>
#include <hip/hip_bf16.h>

typedef short short8 __attribute__((ext_vector_type(8)));
typedef float f32x4 __attribute__((ext_vector_type(4)));
typedef int   i32x4 __attribute__((ext_vector_type(4)));
typedef unsigned short ushort_t;
typedef unsigned short ushort4v __attribute__((ext_vector_type(4)));

#define NBLK   2048
#define ROWCAP 96
#define ZENT   (NBLK << 6)   // pad entry -> zero weight block, col 0
#define MFMA_BF16 __builtin_amdgcn_mfma_f32_16x16x32_bf16

__device__ __forceinline__ ushort_t f2bf(float f) {
    unsigned u = __float_as_uint(f);
    u += 0x7FFFu + ((u >> 16) & 1u);   // RTNE
    return (ushort_t)(u >> 16);
}
__device__ __forceinline__ void gll16(const void* g, void* l) {
    __builtin_amdgcn_global_load_lds(
        (const __attribute__((address_space(1))) unsigned*)g,
        (__attribute__((address_space(3))) unsigned*)l, 16, 0, 0);
}

// ================= prep (identical to R8, which passed) =================
__global__ __launch_bounds__(256)
void prep_kernel(const float* __restrict__ x, const float* __restrict__ wblk,
                 const int* __restrict__ brows, const int* __restrict__ bcols,
                 ushort_t* __restrict__ xc, ushort_t* __restrict__ wb,
                 int* __restrict__ bucket, int* __restrict__ bcnt) {
    __shared__ ushort_t pt[4][2048];
    const int bid = blockIdx.x, tid = threadIdx.x;
    const int wv = tid >> 6, lane = tid & 63;

    if (bid < 1024) {
        const int tc = bid * 4 + wv;
        const int cb = tc >> 6, t64 = tc & 63;
        #pragma unroll
        for (int it = 0; it < 8; ++it) {
            int row = it * 8 + (lane >> 3);
            const float* src = x + (size_t)(t64 * 64 + row) * 2048 + cb * 32 + (lane & 7) * 4;
            float4 v = *reinterpret_cast<const float4*>(src);
            ushort4v o; o.x = f2bf(v.x); o.y = f2bf(v.y); o.z = f2bf(v.z); o.w = f2bf(v.w);
            int m = row >> 4, l15v = row & 15, hi = (lane & 7) >> 1;
            int cc = m * 64 + hi * 16 + l15v;
            *reinterpret_cast<ushort4v*>(&pt[wv][cc * 8 + (lane & 1) * 4]) = o;
        }
        #pragma unroll
        for (int rr = 0; rr < 4; ++rr) {
            i32x4 d = *reinterpret_cast<const i32x4*>(&pt[wv][(rr * 64 + lane) * 8]);
            *reinterpret_cast<i32x4*>(xc + (size_t)tc * 2048 + (rr * 64 + lane) * 8) = d;
        }
    } else if (bid < 2048) {
        int d = (bid - 1024) * 256 + tid;
        int n = d >> 7, cc = d & 127;
        int nsub = cc >> 6, ln = cc & 63;
        int o_ = nsub * 16 + (ln & 15), kc = ln >> 4;
        const float* src = wblk + (size_t)n * 1024 + o_ * 32 + kc * 8;
        float4 v0 = *reinterpret_cast<const float4*>(src);
        float4 v1 = *reinterpret_cast<const float4*>(src + 4);
        short8 o8;
        o8[0] = f2bf(v0.x); o8[1] = f2bf(v0.y); o8[2] = f2bf(v0.z); o8[3] = f2bf(v0.w);
        o8[4] = f2bf(v1.x); o8[5] = f2bf(v1.y); o8[6] = f2bf(v1.z); o8[7] = f2bf(v1.w);
        reinterpret_cast<short8*>(wb)[d] = o8;
    } else if (bid == 2048) {
        if (tid < 128) {
            short8 z = (short8){0,0,0,0,0,0,0,0};
            reinterpret_cast<short8*>(wb + (size_t)NBLK * 1024)[tid] = z;
        }
    } else {
        const int r = (bid - 2049) * 4 + wv;
        const int per = NBLK / 64;
        const int base = lane * per;
        int cnt = 0;
        for (int k = 0; k < per; ++k) cnt += (brows[base + k] == r) ? 1 : 0;
        int sum = cnt;
        for (int d = 1; d < 64; d <<= 1) {
            int v = __shfl_up(sum, d, 64);
            if (lane >= d) sum += v;
        }
        int off = sum - cnt;
        for (int k = 0; k < per; ++k) {
            int n = base + k;
            if (brows[n] == r) bucket[r * ROWCAP + (off++)] = (n << 6) | bcols[n];
        }
        int total = __shfl(sum, 63, 64);
        if (lane < 8) bucket[r * ROWCAP + total + lane] = ZENT;
        if (lane == 0) bcnt[r] = total;
    }
}

// ================= main kernel (R8 chassis, L2-locality remap) =================
// 1024 WGs x 128 thr (2 waves). Wave job = (row r, 128-token slab).
// NEW MAP: q=wg&7 pins ROWS to XCDs (W slice 512 KB -> L2-resident);
// slab is dispatch-outermost so the 4 WGs of each (XCD, slab) are co-resident
// and share A strips through L2. Pipeline identical to R8 (passed):
// per-wave private depth-3 LDS ring, counted vmcnt(10), no barriers.
#define DSR(d, a, o) asm volatile("ds_read_b128 %0, %1 offset:" #o : "=v"(d) : "v"(a))

#define SUBITER(FB, SPX, EX) do {                                              \
    short8 a0,a1,a2,a3,a4,a5,a6,a7,b0,b1;                                      \
    asm volatile("s_waitcnt vmcnt(10)" ::: "memory");                          \
    DSR(a0, FB, 0);    DSR(a1, FB, 1024); DSR(a2, FB, 2048); DSR(a3, FB, 3072);\
    DSR(a4, FB, 4096); DSR(a5, FB, 5120); DSR(a6, FB, 6144); DSR(a7, FB, 7168);\
    DSR(b0, FB, 8192); DSR(b1, FB, 9216);                                      \
    STAGE(SPX, EX);                                                            \
    asm volatile("ds_read_b32 %0, %1" : "=v"(EX) : "v"(laddr) : "memory");     \
    laddr += 4;                                                                \
    asm volatile("s_waitcnt lgkmcnt(0)" ::: "memory");                         \
    __builtin_amdgcn_sched_barrier(0);                                         \
    __builtin_amdgcn_s_setprio(1);                                             \
    acc[0][0] = MFMA_BF16(a0, b0, acc[0][0], 0,0,0);                           \
    acc[0][1] = MFMA_BF16(a0, b1, acc[0][1], 0,0,0);                           \
    acc[1][0] = MFMA_BF16(a1, b0, acc[1][0], 0,0,0);                           \
    acc[1][1] = MFMA_BF16(a1, b1, acc[1][1], 0,0,0);                           \
    acc[2][0] = MFMA_BF16(a2, b0, acc[2][0], 0,0,0);                           \
    acc[2][1] = MFMA_BF16(a2, b1, acc[2][1], 0,0,0);                           \
    acc[3][0] = MFMA_BF16(a3, b0, acc[3][0], 0,0,0);                           \
    acc[3][1] = MFMA_BF16(a3, b1, acc[3][1], 0,0,0);                           \
    acc[4][0] = MFMA_BF16(a4, b0, acc[4][0], 0,0,0);                           \
    acc[4][1] = MFMA_BF16(a4, b1, acc[4][1], 0,0,0);                           \
    acc[5][0] = MFMA_BF16(a5, b0, acc[5][0], 0,0,0);                           \
    acc[5][1] = MFMA_BF16(a5, b1, acc[5][1], 0,0,0);                           \
    acc[6][0] = MFMA_BF16(a6, b0, acc[6][0], 0,0,0);                           \
    acc[6][1] = MFMA_BF16(a6, b1, acc[6][1], 0,0,0);                           \
    acc[7][0] = MFMA_BF16(a7, b0, acc[7][0], 0,0,0);                           \
    acc[7][1] = MFMA_BF16(a7, b1, acc[7][1], 0,0,0);                           \
    __builtin_amdgcn_s_setprio(0);                                             \
} while (0)

__global__ __launch_bounds__(128)
void bsl_mfma_kernel(const ushort_t* __restrict__ xc,
                     const ushort_t* __restrict__ wb,
                     const int* __restrict__ bucket,
                     const int* __restrict__ bcnt,
                     float* __restrict__ out) {
    __shared__ ushort_t ring[2][3][5120];   // per wave: 3 slots x (A 8KB + B 2KB)
    __shared__ int      llist[2][96];

    const int wg   = blockIdx.x;            // [0,1024)
    const int q    = wg & 7;                // XCD residue -> ROW group (W L2-pinned)
    const int i    = wg >> 3;               // [0,128)
    const int slab = i >> 2;                // [0,32): dispatch-outermost -> A time-window
    const int rp   = i & 3;                 // row-pair within XCD
    const int tid  = threadIdx.x;
    const int wv   = tid >> 6, lane = tid & 63;
    const int r    = q * 8 + rp * 2 + wv;   // [0,64): output row-block
    const int l15  = lane & 15, hi = lane >> 4;
    const int tok0 = slab * 128;

    const int cnt = bcnt[r];

    // ---- list -> LDS (lgkm path; keeps vmcnt clean in the loop)
    int lv = 0;
    if (lane < ROWCAP) lv = bucket[r * ROWCAP + lane];
    asm volatile("s_waitcnt vmcnt(0)" ::: "memory");
    if (lane < ROWCAP) llist[wv][lane] = lv;
    int e0 = llist[wv][0], e1 = llist[wv][1];
    int ea = llist[wv][2], eb = llist[wv][3], ec = llist[wv][4];

    const ushort_t* xsrc = xc + lane * 8;
    const ushort_t* wsrc = wb + lane * 8;
    ushort_t* sp0 = &ring[wv][0][0];
    ushort_t* sp1 = &ring[wv][1][0];
    ushort_t* sp2 = &ring[wv][2][0];

    auto STAGE = [&](ushort_t* sp, int e) {
        int eu = __builtin_amdgcn_readfirstlane(e);
        const ushort_t* as = xsrc + ((size_t)((eu & 63) * 64 + 2 * slab) << 11);
        const ushort_t* bs = wsrc + ((size_t)(eu >> 6) << 10);
        #pragma unroll
        for (int t = 0; t < 8; ++t) gll16(as + t * 512, sp + t * 512);
        gll16(bs,       sp + 4096);
        gll16(bs + 512, sp + 4608);
    };

    f32x4 acc[8][2];
    #pragma unroll
    for (int m = 0; m < 8; ++m) {
        acc[m][0] = (f32x4){0.f, 0.f, 0.f, 0.f};
        acc[m][1] = (f32x4){0.f, 0.f, 0.f, 0.f};
    }

    unsigned fb0 = (unsigned)(size_t)&ring[wv][0][0] + lane * 16;
    unsigned fb1 = fb0 + 10240;
    unsigned fb2 = fb0 + 20480;
    unsigned laddr = (unsigned)(size_t)&llist[wv][0] + 5 * 4;

    STAGE(sp0, e0);
    STAGE(sp1, e1);

    const int cnt3 = ((cnt + 2) / 3) * 3;   // pads are zero-W blocks
    for (int j = 0; j < cnt3; j += 3) {
        SUBITER(fb0, sp2, ea);   // compute slot0, stage slot2 (entry j+2)
        SUBITER(fb1, sp0, eb);   // compute slot1, stage slot0 (entry j+3)
        SUBITER(fb2, sp1, ec);   // compute slot2, stage slot1 (entry j+4)
    }
    asm volatile("s_waitcnt vmcnt(0) lgkmcnt(0)" ::: "memory");

    // C/D layout: col = lane&15, row = (lane>>4)*4 + reg  [HW-verified]
    const int outc = r * 32 + l15;
    #pragma unroll
    for (int m = 0; m < 8; ++m) {
        #pragma unroll
        for (int ns = 0; ns < 2; ++ns) {
            #pragma unroll
            for (int reg = 0; reg < 4; ++reg) {
                int token = tok0 + m * 16 + hi * 4 + reg;
                out[(size_t)token * 2048 + outc + ns * 16] = acc[m][ns][reg];
            }
        }
    }
}

extern "C" void kernel_launch(void* const* d_in, const int* in_sizes, int n_in,
                              void* d_out, int out_size, void* d_ws, size_t ws_size,
                              hipStream_t stream) {
    const float* x     = (const float*)d_in[0];
    const float* wblk  = (const float*)d_in[1];
    const int*   brows = (const int*)d_in[2];
    const int*   bcols = (const int*)d_in[3];
    float*       out   = (float*)d_out;

    char* ws = (char*)d_ws;
    ushort_t* xc     = (ushort_t*)(ws);                    // 16,777,216 B
    ushort_t* wb     = (ushort_t*)(ws + 16777216);         //  4,196,352 B (2049 blocks)
    int*      bucket = (int*)(ws + 20973568);              //     24,576 B (64 x 96)
    int*      bcnt   = (int*)(ws + 20998144);              //        256 B

    // 1024 (x tiles) + 1024 (w cvt) + 1 (zero blk) + 16 (bucketize)
    prep_kernel<<<2065, 256, 0, stream>>>(x, wblk, brows, bcols, xc, wb, bucket, bcnt);
    bsl_mfma_kernel<<<1024, 128, 0, stream>>>(xc, wb, bucket, bcnt, out);
}